// Round 1
// baseline (161.870 us; speedup 1.0000x reference)
//
#include <hip/hip_runtime.h>

// ChebyshevAdditiveAngularMargin
//   cosine = clip(outputs, -1+1e-7, 1-1e-7)
//   phi    = clenshaw(cosine, coeffs)           (Chebyshev, degree 30)
//   phi    = cosine > TH ? phi : cosine - MM     (TH = cos(pi-0.2), MM = sin(0.2)*0.2)
//   out    = 30 * (targets*phi + (1-targets)*cosine)
// targets is one-hot -> phi only matters at 8192 of 64M elements; guard the
// Clenshaw evaluation behind a per-lane branch so ~97% of waves skip it
// (s_cbranch_execz). Kernel is HBM-bound: 768 MB total traffic.

namespace {

constexpr float kClipLo = -0.9999999f;   // -1 + 1e-7 rounded to f32
constexpr float kClipHi =  0.9999999f;   //  1 - 1e-7 rounded to f32
constexpr float kTH     = -0.98006657784124163f;  // cos(pi - 0.2)
constexpr float kMM     =  0.039733866159012243f; // sin(pi - 0.2) * 0.2
constexpr float kSCALE  = 30.0f;
constexpr int   kDegree = 30;            // 31 coefficients

__device__ __forceinline__ float clenshaw_phi(float x, const float* __restrict__ coeffs) {
    // b_k = c_k + 2x*b_{k+1} - b_{k+2}, k = DEGREE..0;  f(x) = b_0 - x*b_1
    const float x2 = 2.0f * x;
    float b1 = 0.0f, b2 = 0.0f;
#pragma unroll
    for (int k = kDegree; k >= 0; --k) {
        float b = coeffs[k] + x2 * b1 - b2;
        b2 = b1;
        b1 = b;
    }
    return b1 - b2 * x;
}

__global__ __launch_bounds__(256) void cheb_aam_kernel(
    const float4* __restrict__ outputs4,
    const float4* __restrict__ targets4,
    const float*  __restrict__ coeffs,
    float4*       __restrict__ dst4,
    int n4) {
    const int tid    = blockIdx.x * blockDim.x + threadIdx.x;
    const int stride = gridDim.x * blockDim.x;

    for (int i = tid; i < n4; i += stride) {
        const float4 o = outputs4[i];
        const float4 t = targets4[i];

        float xs[4] = {o.x, o.y, o.z, o.w};
        float ts[4] = {t.x, t.y, t.z, t.w};
        float rs[4];

#pragma unroll
        for (int j = 0; j < 4; ++j) {
            const float x = fminf(fmaxf(xs[j], kClipLo), kClipHi);
            float r = x;  // targets == 0 path: out = cosine
            if (ts[j] != 0.0f) {
                // rare path: one element per row of 8192
                const float phi = (x > kTH) ? clenshaw_phi(x, coeffs) : (x - kMM);
                r = ts[j] * phi + (1.0f - ts[j]) * x;
            }
            rs[j] = kSCALE * r;
        }

        dst4[i] = make_float4(rs[0], rs[1], rs[2], rs[3]);
    }
}

}  // namespace

extern "C" void kernel_launch(void* const* d_in, const int* in_sizes, int n_in,
                              void* d_out, int out_size, void* d_ws, size_t ws_size,
                              hipStream_t stream) {
    const float* outputs = (const float*)d_in[0];
    const float* targets = (const float*)d_in[1];
    const float* coeffs  = (const float*)d_in[2];
    float* dst = (float*)d_out;

    const int n  = out_size;       // 8192*8192, divisible by 4
    const int n4 = n / 4;

    const int block = 256;
    int grid = (n4 + block - 1) / block;
    if (grid > 2048) grid = 2048;  // grid-stride the rest (G11)

    cheb_aam_kernel<<<grid, block, 0, stream>>>(
        (const float4*)outputs, (const float4*)targets, coeffs,
        (float4*)dst, n4);
}